// Round 9
// baseline (150.941 us; speedup 1.0000x reference)
//
#include <hip/hip_runtime.h>
#include <cmath>
#include <cstdint>

#define BATCH  256
#define TT     1024
#define FIN    16
#define TC     32
#define NCHUNK (TT / TC)          // 32
#define SROW   324                // s_h row stride (f32): 256 bulk(padded-4) + 64 coh + 4 pad
#define YSS    328                // s_y row stride (bf16): 164 words, 164%32==4 -> out b128 reads free
#define HB     16                 // bulk half-burst depth

typedef __attribute__((ext_vector_type(8))) short short8;
typedef __attribute__((ext_vector_type(4))) float floatx4;

__device__ __forceinline__ unsigned short f2bf_rne(float f) {
    union { float f; unsigned int i; } v; v.f = f;
    unsigned int b = v.i;
    return (unsigned short)((b + 0x7FFFu + ((b >> 16) & 1u)) >> 16);
}
__device__ __forceinline__ float u2f(unsigned int u) {
    union { unsigned int i; float f; } v; v.i = u; return v.f;
}

#define SBAR()  __builtin_amdgcn_sched_barrier(0)
// consumer-side fence: nothing (esp. LDS data reads) may be reordered above the poll
#define ACQ()   asm volatile("" ::: "memory")
// producer-side: drain LDS data ops before the flag store
#define REL()   asm volatile("s_waitcnt lgkmcnt(0)" ::: "memory")

// Material constants (plane stress)
#define MC00   219.78021978021977f
#define MC01   65.93406593406593f
#define MC22   76.92307692307692f
#define MSY0   2.0f
#define AK     0.958466453674121406f  // 3G/(3G+H)
#define BK     0.041533546325878594f  // H/(3G+H)

// Wave roles (8 waves; SIMD s hosts wv s and s+4):
//  wv0: bulk scan  | wv4: out-GEMM mt0     wv1: coh scan | wv5: out-GEMM mt1
//  wv2: h n=0..4   | wv6: h n=10..14       wv3: h n=5..9 | wv7: h n=15..19
// NO global barriers in the main loop: point-to-point LDS flag handshakes.
// Flags (monotone chunk counters): 0..3 h-ready[hw]; 4 bulk-consumed-h;
// 5 coh-consumed-h; 6 y-bulk-ready; 7 y-coh-ready; 8,9 y-consumed[mt].
// Wait graph is a DAG in chunk index -> deadlock-free; all waves co-resident
// (1 block/CU) -> spin-wait safe. Producers: data -> lgkmcnt(0) -> flag.

__global__ __launch_bounds__(512, 2)
void fused_mat_kernel(const float* __restrict__ x,
                      const float* __restrict__ w1,
                      const float* __restrict__ w2,
                      float* __restrict__ out)
{
    __shared__ __attribute__((aligned(16))) float          s_h[2][TC][SROW];
    __shared__ __attribute__((aligned(16))) unsigned short s_y[2][TC][YSS];
    __shared__ int flg[16];

    volatile int* F = (volatile int*)flg;

    const int tid  = threadIdx.x;
    const int b    = blockIdx.x;
    const int lane = tid & 63;
    const int wv   = tid >> 6;    // 0..7
    const int m    = lane & 15;
    const int q    = lane >> 4;

    const size_t xrow = (size_t)b * TT;

    const bool isG   = (wv == 2) | (wv == 3) | (wv == 6) | (wv == 7);
    const int  hw    = (wv == 2) ? 0 : (wv == 3) ? 1 : (wv == 6) ? 2 : 3;
    const int  nbase = hw * 5;                               // 0 / 5 / 10 / 15

    short8 wfrag[5];  // h-GEMM waves: my 5 W1 A-fragments
    short8 vf[10];    // out-GEMM waves (permuted-k layout)
    uint4  rxc[2][2], rxp[2][2];  // h-GEMM: raw x bits, cur/prev row, per M-tile

    if (tid == 0) {   // nothing-consumed-yet tokens (vacuously free buffers)
        flg[4] = -1; flg[5] = -1; flg[6] = -1; flg[7] = -1; flg[8] = -1; flg[9] = -1;
    }

    // h-chunk emit: swapped-operand MFMA -> C[col=t][row=l'] -> b128 row writes.
    auto emit = [&](const short8* axv, const short8* adxv, float* dst) {
        #pragma unroll
        for (int mt = 0; mt < 2; ++mt) {
            float* drow = dst + (mt * 16 + m) * SROW + q * 4 + nbase * 16;
            #pragma unroll
            for (int j = 0; j < 5; ++j) {
                const int n = nbase + j;
                floatx4 acc = {0.f, 0.f, 0.f, 0.f};
                acc = __builtin_amdgcn_mfma_f32_16x16x32_bf16(
                        wfrag[j], (n < 16) ? adxv[mt] : axv[mt], acc, 0, 0, 0);
                *(floatx4*)(drow + j * 16) = acc;  // ds_write_b128, imm offset
            }
        }
    };

    if (isG) {
        // ---- my W1 A-fragment slice (folded for n<16, plain for n>=16) ----
        #pragma unroll
        for (int j = 0; j < 5; ++j) {
            const int n = nbase + j;
            #pragma unroll
            for (int jj = 0; jj < 8; ++jj) {
                float v = 0.f;
                if (q < 2) {
                    const int f = q * 8 + jj;
                    if (n < 16) {
                        const int lp = n * 16 + m, c = lp >> 2, cm = lp & 3;
                        if (cm < 3) {
                            const float wa  = w1[(3 * c + 0) * FIN + f];
                            const float wb  = w1[(3 * c + 1) * FIN + f];
                            const float wcc = w1[(3 * c + 2) * FIN + f];
                            v = (cm == 0) ? fmaf(MC01, wb, MC00 * wa)
                              : (cm == 1) ? fmaf(MC00, wb, MC01 * wa)
                                          : MC22 * wcc;
                        }
                    } else {
                        v = w1[(192 + (n - 16) * 16 + m) * FIN + f];
                    }
                }
                wfrag[j][jj] = (short)f2bf_rne(v);
            }
        }
        // ---- prologue: chunk 0 fragments (guarded scalar loads, rowB==0 edge) ----
        short8 ax0[2], adx0[2];
        #pragma unroll
        for (int mt = 0; mt < 2; ++mt) {
            #pragma unroll
            for (int j = 0; j < 8; ++j) {
                float xc = 0.f, xp = 0.f;
                if (q < 2) {
                    const int rowB = mt * 16 + m;
                    xc = x[(xrow + rowB) * FIN + q * 8 + j];
                    if (rowB > 0) xp = x[(xrow + rowB - 1) * FIN + q * 8 + j];
                }
                ax0[mt][j]  = (short)f2bf_rne(xc);
                adx0[mt][j] = (short)f2bf_rne(xc - xp);
            }
        }
        // prefetch raw x rows for chunk 1
        if (q < 2) {
            #pragma unroll
            for (int mt = 0; mt < 2; ++mt) {
                const int rowB = TC + mt * 16 + m;
                const float* xc = x + (xrow + rowB) * FIN + q * 8;
                const float* xp = x + (xrow + rowB - 1) * FIN + q * 8;
                rxc[mt][0] = *(const uint4*)xc;  rxc[mt][1] = *(const uint4*)(xc + 4);
                rxp[mt][0] = *(const uint4*)xp;  rxp[mt][1] = *(const uint4*)(xp + 4);
            }
        }
        emit(ax0, adx0, &s_h[0][0][0]);
        if (lane == 0) flg[hw] = 0;   // chunk 0 ready (visibility via __syncthreads)
    } else if (wv == 4 || wv == 5) {
        #pragma unroll
        for (int ks = 0; ks < 10; ++ks) {
            #pragma unroll
            for (int j = 0; j < 8; ++j) {
                const int p = ks * 32 + q * 8 + j;
                unsigned short v = 0;
                if (p < 256) {
                    const int comp = p & 3;
                    if (comp < 3) {
                        const int l = 3 * (p >> 2) + comp;
                        float xv = w2[m * 256 + l];
                        float sp = fmaxf(xv, 0.0f) + log1pf(expf(-fabsf(xv)));
                        v = f2bf_rne(sp);
                    }
                } else {
                    const int l = p - 64;  // 192 + (p-256)
                    float xv = w2[m * 256 + l];
                    float sp = fmaxf(xv, 0.0f) + log1pf(expf(-fabsf(xv)));
                    v = f2bf_rne(sp);
                }
                vf[ks][j] = (short)v;
            }
        }
    }

    // material state
    float tt0 = 0.f, tt1 = 0.f, tt2 = 0.f, rr = 1.0f, syv = MSY0, pre = AK * MSY0;
    float hist = 0.f;  // coh wave

    __syncthreads();   // chunk 0 + flag init visible (the ONLY full barrier)

    if (wv == 0) {                     // ---------------- bulk scan ----------------
        for (int i = 0; i < NCHUNK; ++i) {
            while (F[0] < i) {} while (F[1] < i) {} while (F[2] < i) {} while (F[3] < i) {}
            const int yf = i - 2;
            while (F[8] < yf) {} while (F[9] < yf) {}
            ACQ();
            const float* hb = &s_h[i & 1][0][0] + 4 * lane;
            unsigned short* yb = &s_y[i & 1][0][0] + 4 * lane;
            floatx4 dvvA[HB], dvvB[HB];
            uint2   yreg[TC];
            #pragma unroll
            for (int t = 0; t < HB; ++t) dvvA[t] = *(const floatx4*)(hb + t * SROW);
            SBAR();
            #pragma unroll
            for (int t = 0; t < HB; ++t) dvvB[t] = *(const floatx4*)(hb + (HB + t) * SROW);
            SBAR();
            #pragma unroll
            for (int t = 0; t < TC; ++t) {
                const floatx4 dv = (t < HB) ? dvvA[t] : dvvB[t - HB];
                tt0 = fmaf(rr, tt0, dv.x);
                tt1 = fmaf(rr, tt1, dv.y);
                tt2 = fmaf(rr, tt2, dv.z);
                const float s01 = tt0 - tt1;
                const float u   = tt2 * tt2;
                const float w3  = fmaf(u, 3.0f, 1e-12f);          // clamp absorbed (PSD form)
                const float bb  = fmaf(tt1, tt1, w3);
                const float qq  = fmaf(tt0, s01, bb);
                const float rs  = __builtin_amdgcn_rsqf(qq);
                const float seq = qq * rs;
                rr  = fminf(fmaf(pre, rs, BK), 1.0f);
                syv = fmaxf(syv, fmaf(BK, seq, pre));             // = max(syv, AK*syv+BK*seq)
                pre = AK * syv;
                const float sg0 = rr * tt0, sg1 = rr * tt1, sg2 = rr * tt2;
                unsigned int r0, r1;
                asm("v_cvt_pk_bf16_f32 %0, %1, %2" : "=v"(r0) : "v"(sg0), "v"(sg1));
                asm("v_cvt_pk_bf16_f32 %0, %1, %2" : "=v"(r1) : "v"(sg2), "v"(sg2));
                yreg[t].x = r0; yreg[t].y = r1;
            }
            SBAR();
            #pragma unroll
            for (int t = 0; t < TC; ++t)
                *(uint2*)(yb + t * YSS) = yreg[t];                // pad slot hits vf==0
            REL();
            if (lane == 0) { F[4] = i; F[6] = i; }
        }
    } else if (wv == 1) {              // ---------------- cohesive scan ----------------
        for (int i = 0; i < NCHUNK; ++i) {
            while (F[3] < i) {}
            const int yf = i - 2;
            while (F[8] < yf) {} while (F[9] < yf) {}
            ACQ();
            if (lane < 32) {
                const float* hc = &s_h[i & 1][0][0] + 256 + 2 * lane;
                unsigned short* yc = &s_y[i & 1][0][0] + 256 + 2 * lane;
                float2 jvv[TC];
                unsigned int yr[TC];
                #pragma unroll
                for (int t = 0; t < TC; ++t) jvv[t] = *(const float2*)(hc + t * SROW);
                SBAR();
                #pragma unroll
                for (int t = 0; t < TC; ++t) {
                    const float dn = jvv[t].x, ds = jvv[t].y;
                    const float dnp = fmaxf(dn, 0.0f);
                    const float lam = __builtin_amdgcn_sqrtf(fmaxf(fmaf(dnp, dnp, ds * ds), 1e-12f));
                    hist = fmaxf(hist, lam);
                    float dmg = (hist - 0.1f) * __builtin_amdgcn_rcpf(hist * 0.9f);
                    dmg = fminf(fmaxf(dmg, 0.0f), 1.0f);
                    const float om = 1.0f - dmg;
                    const float tn = 50.0f * dn * (dn > 0.0f ? om : 1.0f);
                    const float ts = om * 50.0f * ds;
                    unsigned int r;
                    asm("v_cvt_pk_bf16_f32 %0, %1, %2" : "=v"(r) : "v"(tn), "v"(ts));
                    yr[t] = r;
                }
                SBAR();
                #pragma unroll
                for (int t = 0; t < TC; ++t)
                    *(unsigned int*)(yc + t * YSS) = yr[t];
            }
            REL();
            if (lane == 0) { F[5] = i; F[7] = i; }
        }
    } else if (isG) {                  // ---------------- h-GEMM ----------------
        for (int k = 1; k < NCHUNK; ++k) {
            // convert rx (chunk k, loaded last round) -> fragments; no LDS ops here
            short8 ax[2], adx[2];
            #pragma unroll
            for (int mt = 0; mt < 2; ++mt) {
                const unsigned int wc[8] = {rxc[mt][0].x, rxc[mt][0].y, rxc[mt][0].z, rxc[mt][0].w,
                                            rxc[mt][1].x, rxc[mt][1].y, rxc[mt][1].z, rxc[mt][1].w};
                const unsigned int wp[8] = {rxp[mt][0].x, rxp[mt][0].y, rxp[mt][0].z, rxp[mt][0].w,
                                            rxp[mt][1].x, rxp[mt][1].y, rxp[mt][1].z, rxp[mt][1].w};
                union { unsigned int u[4]; short8 s; } Ua, Ud;
                #pragma unroll
                for (int p = 0; p < 4; ++p) {
                    const float c0 = u2f(wc[2 * p]),          c1 = u2f(wc[2 * p + 1]);
                    const float d0 = c0 - u2f(wp[2 * p]),     d1 = c1 - u2f(wp[2 * p + 1]);
                    unsigned int va, vd;
                    asm("v_cvt_pk_bf16_f32 %0, %1, %2" : "=v"(va) : "v"(c0), "v"(c1));
                    asm("v_cvt_pk_bf16_f32 %0, %1, %2" : "=v"(vd) : "v"(d0), "v"(d1));
                    Ua.u[p] = (q < 2) ? va : 0u;   // k>=16 zero-pad lanes
                    Ud.u[p] = (q < 2) ? vd : 0u;
                }
                ax[mt]  = Ua.s;
                adx[mt] = Ud.s;
            }
            // issue raw loads for chunk k+1 (fly across the handshake)
            if (k + 1 < NCHUNK && q < 2) {
                #pragma unroll
                for (int mt = 0; mt < 2; ++mt) {
                    const int rowB = (k + 1) * TC + mt * 16 + m;
                    const float* xc = x + (xrow + rowB) * FIN + q * 8;
                    const float* xp = x + (xrow + rowB - 1) * FIN + q * 8;
                    rxc[mt][0] = *(const uint4*)xc;  rxc[mt][1] = *(const uint4*)(xc + 4);
                    rxp[mt][0] = *(const uint4*)xp;  rxp[mt][1] = *(const uint4*)(xp + 4);
                }
            }
            // buffer-free: scan consumed chunk k-2 from buf[k&1]
            const int hf = k - 2;
            while (F[4] < hf) __builtin_amdgcn_s_sleep(1);
            if (hw == 3) { while (F[5] < hf) __builtin_amdgcn_s_sleep(1); }
            ACQ();
            emit(ax, adx, &s_h[k & 1][0][0]);
            REL();
            if (lane == 0) F[hw] = k;
        }
    } else {                           // ---------------- out-GEMM ----------------
        const int mt = wv - 4;
        for (int j = 0; j < NCHUNK; ++j) {
            while (F[6] < j) __builtin_amdgcn_s_sleep(1);
            while (F[7] < j) __builtin_amdgcn_s_sleep(1);
            ACQ();
            const int tb = j * TC;
            const unsigned short* yb = &s_y[j & 1][0][0];
            floatx4 a0 = {0.f, 0.f, 0.f, 0.f};
            floatx4 a1 = {0.f, 0.f, 0.f, 0.f};
            #pragma unroll
            for (int ks = 0; ks < 5; ++ks) {
                const short8* yp = (const short8*)(yb + (mt * 16 + m) * YSS + ks * 32 + q * 8);
                a0 = __builtin_amdgcn_mfma_f32_16x16x32_bf16(*yp, vf[ks], a0, 0, 0, 0);
            }
            #pragma unroll
            for (int ks = 5; ks < 10; ++ks) {
                const short8* yp = (const short8*)(yb + (mt * 16 + m) * YSS + ks * 32 + q * 8);
                a1 = __builtin_amdgcn_mfma_f32_16x16x32_bf16(*yp, vf[ks], a1, 0, 0, 0);
            }
            #pragma unroll
            for (int r = 0; r < 4; ++r)
                out[(xrow + tb + mt * 16 + q * 4 + r) * FIN + m] = a0[r] + a1[r];
            REL();                     // y-reads retired before releasing the buffer
            if (lane == 0) F[8 + mt] = j;
        }
    }
}

extern "C" void kernel_launch(void* const* d_in, const int* in_sizes, int n_in,
                              void* d_out, int out_size, void* d_ws, size_t ws_size,
                              hipStream_t stream) {
    const float* x  = (const float*)d_in[0];   // [256,1024,16] f32
    const float* w1 = (const float*)d_in[1];   // [256,16] f32
    const float* w2 = (const float*)d_in[2];   // [16,256] f32
    float* out = (float*)d_out;                // [256,1024,16] f32
    fused_mat_kernel<<<BATCH, 512, 0, stream>>>(x, w1, w2, out);
}

// Round 10
// 146.365 us; speedup vs baseline: 1.0313x; 1.0313x over previous
//
#include <hip/hip_runtime.h>
#include <cmath>
#include <cstdint>

#define BATCH  256
#define TT     1024
#define FIN    16
#define TC     32
#define NCHUNK (TT / TC)          // 32
#define SROW   324                // s_h row stride (f32): 256 bulk(padded-4) + 64 coh + 4 pad
#define YSS    328                // s_y row stride (bf16)
#define HB     16                 // bulk half-burst depth

typedef __attribute__((ext_vector_type(8))) short short8;
typedef __attribute__((ext_vector_type(4))) float floatx4;

__device__ __forceinline__ unsigned short f2bf_rne(float f) {
    union { float f; unsigned int i; } v; v.f = f;
    unsigned int b = v.i;
    return (unsigned short)((b + 0x7FFFu + ((b >> 16) & 1u)) >> 16);
}
__device__ __forceinline__ float u2f(unsigned int u) {
    union { unsigned int i; float f; } v; v.i = u; return v.f;
}

#define SBAR()  __builtin_amdgcn_sched_barrier(0)
#define ACQ()   asm volatile("" ::: "memory")
#define REL()   asm volatile("s_waitcnt lgkmcnt(0)" ::: "memory")

// batched polls: issue all flag reads, ONE waitcnt, compare; sleep only on retry
#define POLL4GE(i0, val) \
    for (;;) { int f0_=F[i0], f1_=F[(i0)+1], f2_=F[(i0)+2], f3_=F[(i0)+3]; \
        if (f0_>=(val) && f1_>=(val) && f2_>=(val) && f3_>=(val)) break; \
        __builtin_amdgcn_s_sleep(1); }
#define POLL2GE(i0, val) \
    for (;;) { int f0_=F[i0], f1_=F[(i0)+1]; \
        if (f0_>=(val) && f1_>=(val)) break; \
        __builtin_amdgcn_s_sleep(1); }
#define POLL1GE(i0, val) \
    for (;;) { int f0_=F[i0]; if (f0_>=(val)) break; __builtin_amdgcn_s_sleep(1); }

// Material constants (plane stress)
#define MC00   219.78021978021977f
#define MC01   65.93406593406593f
#define MC22   76.92307692307692f
#define MSY0   2.0f
#define AK     0.958466453674121406f  // 3G/(3G+H)
#define BK     0.041533546325878594f  // H/(3G+H)

// Wave roles (8 waves; SIMD s hosts wv s and s+4):
//  wv0: bulk scan  | wv4: out-GEMM mt0     wv1: coh scan | wv5: out-GEMM mt1
//  wv2: h n=0..4   | wv6: h n=10..14       wv3: h n=5..9 | wv7: h n=15..19
// Flag protocol (monotone chunk counters in LDS):
//  0..3 h-ready[hw]; 4 bulk-read-h-done; 5 coh-read-h-done;
//  6 y-bulk-ready; 7 y-coh-ready; 8,9 y-consumed[mt].
// Consumers signal "h consumed" right after their read burst drains, giving
// producers a head start; y-free polls sit AFTER the compute chain.

__global__ __launch_bounds__(512, 2)
void fused_mat_kernel(const float* __restrict__ x,
                      const float* __restrict__ w1,
                      const float* __restrict__ w2,
                      float* __restrict__ out)
{
    __shared__ __attribute__((aligned(16))) float          s_h[2][TC][SROW];
    __shared__ __attribute__((aligned(16))) unsigned short s_y[2][TC][YSS];
    __shared__ int flg[16];

    volatile int* F = (volatile int*)flg;

    const int tid  = threadIdx.x;
    const int b    = blockIdx.x;
    const int lane = tid & 63;
    const int wv   = tid >> 6;    // 0..7
    const int m    = lane & 15;
    const int q    = lane >> 4;

    const size_t xrow = (size_t)b * TT;

    const bool isG   = (wv == 2) | (wv == 3) | (wv == 6) | (wv == 7);
    const int  hw    = (wv == 2) ? 0 : (wv == 3) ? 1 : (wv == 6) ? 2 : 3;
    const int  nbase = hw * 5;                               // 0 / 5 / 10 / 15

    short8 wfrag[5];  // h-GEMM waves: my 5 W1 A-fragments
    short8 vf[10];    // out-GEMM waves (permuted-k layout)
    uint4  rxc[2][2], rxp[2][2];  // h-GEMM: raw x bits, cur/prev row, per M-tile

    if (tid == 0) {   // nothing-consumed-yet tokens (vacuously free buffers)
        flg[4] = -1; flg[5] = -1; flg[6] = -1; flg[7] = -1; flg[8] = -1; flg[9] = -1;
    }

    auto emit = [&](const short8* axv, const short8* adxv, float* dst) {
        #pragma unroll
        for (int mt = 0; mt < 2; ++mt) {
            float* drow = dst + (mt * 16 + m) * SROW + q * 4 + nbase * 16;
            #pragma unroll
            for (int j = 0; j < 5; ++j) {
                const int n = nbase + j;
                floatx4 acc = {0.f, 0.f, 0.f, 0.f};
                acc = __builtin_amdgcn_mfma_f32_16x16x32_bf16(
                        wfrag[j], (n < 16) ? adxv[mt] : axv[mt], acc, 0, 0, 0);
                *(floatx4*)(drow + j * 16) = acc;  // ds_write_b128, imm offset
            }
        }
    };

    if (isG) {
        // ---- my W1 A-fragment slice (folded for n<16, plain for n>=16) ----
        #pragma unroll
        for (int j = 0; j < 5; ++j) {
            const int n = nbase + j;
            #pragma unroll
            for (int jj = 0; jj < 8; ++jj) {
                float v = 0.f;
                if (q < 2) {
                    const int f = q * 8 + jj;
                    if (n < 16) {
                        const int lp = n * 16 + m, c = lp >> 2, cm = lp & 3;
                        if (cm < 3) {
                            const float wa  = w1[(3 * c + 0) * FIN + f];
                            const float wb  = w1[(3 * c + 1) * FIN + f];
                            const float wcc = w1[(3 * c + 2) * FIN + f];
                            v = (cm == 0) ? fmaf(MC01, wb, MC00 * wa)
                              : (cm == 1) ? fmaf(MC00, wb, MC01 * wa)
                                          : MC22 * wcc;
                        }
                    } else {
                        v = w1[(192 + (n - 16) * 16 + m) * FIN + f];
                    }
                }
                wfrag[j][jj] = (short)f2bf_rne(v);
            }
        }
        // ---- prologue: chunk 0 fragments ----
        short8 ax0[2], adx0[2];
        #pragma unroll
        for (int mt = 0; mt < 2; ++mt) {
            #pragma unroll
            for (int j = 0; j < 8; ++j) {
                float xc = 0.f, xp = 0.f;
                if (q < 2) {
                    const int rowB = mt * 16 + m;
                    xc = x[(xrow + rowB) * FIN + q * 8 + j];
                    if (rowB > 0) xp = x[(xrow + rowB - 1) * FIN + q * 8 + j];
                }
                ax0[mt][j]  = (short)f2bf_rne(xc);
                adx0[mt][j] = (short)f2bf_rne(xc - xp);
            }
        }
        if (q < 2) {   // prefetch raw x rows for chunk 1
            #pragma unroll
            for (int mt = 0; mt < 2; ++mt) {
                const int rowB = TC + mt * 16 + m;
                const float* xc = x + (xrow + rowB) * FIN + q * 8;
                const float* xp = x + (xrow + rowB - 1) * FIN + q * 8;
                rxc[mt][0] = *(const uint4*)xc;  rxc[mt][1] = *(const uint4*)(xc + 4);
                rxp[mt][0] = *(const uint4*)xp;  rxp[mt][1] = *(const uint4*)(xp + 4);
            }
        }
        emit(ax0, adx0, &s_h[0][0][0]);
        if (lane == 0) flg[hw] = 0;   // chunk 0 ready (visible via __syncthreads)
    } else if (wv == 4 || wv == 5) {
        #pragma unroll
        for (int ks = 0; ks < 10; ++ks) {
            #pragma unroll
            for (int j = 0; j < 8; ++j) {
                const int p = ks * 32 + q * 8 + j;
                unsigned short v = 0;
                if (p < 256) {
                    const int comp = p & 3;
                    if (comp < 3) {
                        const int l = 3 * (p >> 2) + comp;
                        float xv = w2[m * 256 + l];
                        float sp = fmaxf(xv, 0.0f) + log1pf(expf(-fabsf(xv)));
                        v = f2bf_rne(sp);
                    }
                } else {
                    const int l = p - 64;  // 192 + (p-256)
                    float xv = w2[m * 256 + l];
                    float sp = fmaxf(xv, 0.0f) + log1pf(expf(-fabsf(xv)));
                    v = f2bf_rne(sp);
                }
                vf[ks][j] = (short)v;
            }
        }
    }

    // material state
    float tt0 = 0.f, tt1 = 0.f, tt2 = 0.f, rr = 1.0f, syv = MSY0, pre = AK * MSY0;
    float hist = 0.f;  // coh wave

    __syncthreads();   // chunk 0 + flag init visible (the ONLY full barrier)

    if (wv == 0) {                     // ---------------- bulk scan ----------------
        for (int i = 0; i < NCHUNK; ++i) {
            POLL4GE(0, i);             // h(i) ready (steady state: first check passes)
            ACQ();
            const float* hb = &s_h[i & 1][0][0] + 4 * lane;
            unsigned short* yb = &s_y[i & 1][0][0] + 4 * lane;
            floatx4 dvvA[HB], dvvB[HB];
            uint2   yreg[TC];
            #pragma unroll
            for (int t = 0; t < HB; ++t) dvvA[t] = *(const floatx4*)(hb + t * SROW);
            SBAR();
            #pragma unroll
            for (int t = 0; t < HB; ++t) dvvB[t] = *(const floatx4*)(hb + (HB + t) * SROW);
            REL();                     // reads drained -> release h buffer early
            if (lane == 0) F[4] = i;
            SBAR();
            #pragma unroll
            for (int t = 0; t < TC; ++t) {
                const floatx4 dv = (t < HB) ? dvvA[t] : dvvB[t - HB];
                tt0 = fmaf(rr, tt0, dv.x);
                tt1 = fmaf(rr, tt1, dv.y);
                tt2 = fmaf(rr, tt2, dv.z);
                const float s01 = tt0 - tt1;
                const float u   = tt2 * tt2;
                const float w3  = fmaf(u, 3.0f, 1e-12f);          // clamp absorbed (PSD form)
                const float bb  = fmaf(tt1, tt1, w3);
                const float qq  = fmaf(tt0, s01, bb);
                const float rs  = __builtin_amdgcn_rsqf(qq);
                const float seq = qq * rs;
                rr  = fminf(fmaf(pre, rs, BK), 1.0f);
                syv = fmaxf(syv, fmaf(BK, seq, pre));             // = max(syv, AK*syv+BK*seq)
                pre = AK * syv;
                const float sg0 = rr * tt0, sg1 = rr * tt1, sg2 = rr * tt2;
                unsigned int r0, r1;
                asm("v_cvt_pk_bf16_f32 %0, %1, %2" : "=v"(r0) : "v"(sg0), "v"(sg1));
                asm("v_cvt_pk_bf16_f32 %0, %1, %2" : "=v"(r1) : "v"(sg2), "v"(sg2));
                yreg[t].x = r0; yreg[t].y = r1;
            }
            SBAR();
            POLL2GE(8, i - 2);         // y buffer free (checked only now)
            ACQ();
            #pragma unroll
            for (int t = 0; t < TC; ++t)
                *(uint2*)(yb + t * YSS) = yreg[t];                // pad slot hits vf==0
            REL();
            if (lane == 0) F[6] = i;
        }
    } else if (wv == 1) {              // ---------------- cohesive scan ----------------
        for (int i = 0; i < NCHUNK; ++i) {
            POLL1GE(3, i);
            ACQ();
            if (lane < 32) {
                const float* hc = &s_h[i & 1][0][0] + 256 + 2 * lane;
                unsigned short* yc = &s_y[i & 1][0][0] + 256 + 2 * lane;
                float2 jvv[TC];
                unsigned int yr[TC];
                #pragma unroll
                for (int t = 0; t < TC; ++t) jvv[t] = *(const float2*)(hc + t * SROW);
                REL();                 // reads drained -> release
                if (lane == 0) F[5] = i;
                SBAR();
                #pragma unroll
                for (int t = 0; t < TC; ++t) {
                    const float dn = jvv[t].x, ds = jvv[t].y;
                    const float dnp = fmaxf(dn, 0.0f);
                    const float lam = __builtin_amdgcn_sqrtf(fmaxf(fmaf(dnp, dnp, ds * ds), 1e-12f));
                    hist = fmaxf(hist, lam);
                    float dmg = (hist - 0.1f) * __builtin_amdgcn_rcpf(hist * 0.9f);
                    dmg = fminf(fmaxf(dmg, 0.0f), 1.0f);
                    const float om = 1.0f - dmg;
                    const float tn = 50.0f * dn * (dn > 0.0f ? om : 1.0f);
                    const float ts = om * 50.0f * ds;
                    unsigned int r;
                    asm("v_cvt_pk_bf16_f32 %0, %1, %2" : "=v"(r) : "v"(tn), "v"(ts));
                    yr[t] = r;
                }
                SBAR();
                POLL2GE(8, i - 2);
                ACQ();
                #pragma unroll
                for (int t = 0; t < TC; ++t)
                    *(unsigned int*)(yc + t * YSS) = yr[t];
            } else {
                if (lane == 32) { POLL1GE(3, i); }   // keep wave converged cheaply
            }
            REL();
            if (lane == 0) F[7] = i;
        }
    } else if (isG) {                  // ---------------- h-GEMM ----------------
        for (int k = 1; k < NCHUNK; ++k) {
            short8 ax[2], adx[2];
            #pragma unroll
            for (int mt = 0; mt < 2; ++mt) {
                const unsigned int wc[8] = {rxc[mt][0].x, rxc[mt][0].y, rxc[mt][0].z, rxc[mt][0].w,
                                            rxc[mt][1].x, rxc[mt][1].y, rxc[mt][1].z, rxc[mt][1].w};
                const unsigned int wp[8] = {rxp[mt][0].x, rxp[mt][0].y, rxp[mt][0].z, rxp[mt][0].w,
                                            rxp[mt][1].x, rxp[mt][1].y, rxp[mt][1].z, rxp[mt][1].w};
                union { unsigned int u[4]; short8 s; } Ua, Ud;
                #pragma unroll
                for (int p = 0; p < 4; ++p) {
                    const float c0 = u2f(wc[2 * p]),          c1 = u2f(wc[2 * p + 1]);
                    const float d0 = c0 - u2f(wp[2 * p]),     d1 = c1 - u2f(wp[2 * p + 1]);
                    unsigned int va, vd;
                    asm("v_cvt_pk_bf16_f32 %0, %1, %2" : "=v"(va) : "v"(c0), "v"(c1));
                    asm("v_cvt_pk_bf16_f32 %0, %1, %2" : "=v"(vd) : "v"(d0), "v"(d1));
                    Ua.u[p] = (q < 2) ? va : 0u;   // k>=16 zero-pad lanes
                    Ud.u[p] = (q < 2) ? vd : 0u;
                }
                ax[mt]  = Ua.s;
                adx[mt] = Ud.s;
            }
            if (k + 1 < NCHUNK && q < 2) {   // raw loads for chunk k+1 stay in flight
                #pragma unroll
                for (int mt = 0; mt < 2; ++mt) {
                    const int rowB = (k + 1) * TC + mt * 16 + m;
                    const float* xc = x + (xrow + rowB) * FIN + q * 8;
                    const float* xp = x + (xrow + rowB - 1) * FIN + q * 8;
                    rxc[mt][0] = *(const uint4*)xc;  rxc[mt][1] = *(const uint4*)(xc + 4);
                    rxp[mt][0] = *(const uint4*)xp;  rxp[mt][1] = *(const uint4*)(xp + 4);
                }
            }
            const int hf = k - 2;      // buffer-free: consumers read chunk k-2
            if (hw == 3) { POLL2GE(4, hf); }
            else        { POLL1GE(4, hf); }
            ACQ();
            emit(ax, adx, &s_h[k & 1][0][0]);
            REL();
            if (lane == 0) F[hw] = k;
        }
    } else {                           // ---------------- out-GEMM ----------------
        const int mt = wv - 4;
        for (int j = 0; j < NCHUNK; ++j) {
            POLL2GE(6, j);
            ACQ();
            const int tb = j * TC;
            const unsigned short* yb = &s_y[j & 1][0][0];
            floatx4 a0 = {0.f, 0.f, 0.f, 0.f};
            floatx4 a1 = {0.f, 0.f, 0.f, 0.f};
            #pragma unroll
            for (int ks = 0; ks < 5; ++ks) {
                const short8* yp = (const short8*)(yb + (mt * 16 + m) * YSS + ks * 32 + q * 8);
                a0 = __builtin_amdgcn_mfma_f32_16x16x32_bf16(*yp, vf[ks], a0, 0, 0, 0);
            }
            #pragma unroll
            for (int ks = 5; ks < 10; ++ks) {
                const short8* yp = (const short8*)(yb + (mt * 16 + m) * YSS + ks * 32 + q * 8);
                a1 = __builtin_amdgcn_mfma_f32_16x16x32_bf16(*yp, vf[ks], a1, 0, 0, 0);
            }
            #pragma unroll
            for (int r = 0; r < 4; ++r)
                out[(xrow + tb + mt * 16 + q * 4 + r) * FIN + m] = a0[r] + a1[r];
            REL();                     // y-reads retired before releasing the buffer
            if (lane == 0) F[8 + mt] = j;
        }
    }
}

extern "C" void kernel_launch(void* const* d_in, const int* in_sizes, int n_in,
                              void* d_out, int out_size, void* d_ws, size_t ws_size,
                              hipStream_t stream) {
    const float* x  = (const float*)d_in[0];   // [256,1024,16] f32
    const float* w1 = (const float*)d_in[1];   // [256,16] f32
    const float* w2 = (const float*)d_in[2];   // [16,256] f32
    float* out = (float*)d_out;                // [256,1024,16] f32
    fused_mat_kernel<<<BATCH, 512, 0, stream>>>(x, w1, w2, out);
}

// Round 11
// 140.706 us; speedup vs baseline: 1.0727x; 1.0402x over previous
//
#include <hip/hip_runtime.h>
#include <cmath>
#include <cstdint>

#define BATCH  256
#define TT     1024
#define FIN    16
#define TC     32
#define NCHUNK (TT / TC)          // 32
#define SROW   324                // s_h row stride (f32): 256 bulk(padded-4) + 64 coh + 4 pad
#define YSS    328                // s_y row stride (bf16): 164 words, 164%32==4 -> out b128 reads free
#define HB     16                 // bulk half-burst depth

typedef __attribute__((ext_vector_type(8))) short short8;
typedef __attribute__((ext_vector_type(4))) float floatx4;

__device__ __forceinline__ unsigned short f2bf_rne(float f) {
    union { float f; unsigned int i; } v; v.f = f;
    unsigned int b = v.i;
    return (unsigned short)((b + 0x7FFFu + ((b >> 16) & 1u)) >> 16);
}
__device__ __forceinline__ float u2f(unsigned int u) {
    union { unsigned int i; float f; } v; v.i = u; return v.f;
}

// raw barrier: LDS-ordered only — global loads/stores stay in flight
#define BARRIER() asm volatile("s_waitcnt lgkmcnt(0)\n\ts_barrier" ::: "memory")
#define SBAR()    __builtin_amdgcn_sched_barrier(0)

// Material constants (plane stress)
#define MC00   219.78021978021977f
#define MC01   65.93406593406593f
#define MC22   76.92307692307692f
#define MSY0   2.0f
#define AK     0.958466453674121406f  // 3G/(3G+H)
#define BK     0.041533546325878594f  // H/(3G+H)

// Wave roles (8 waves; SIMD s hosts wv s and s+4):
//  wv0: bulk scan (64 lanes)  | SIMD0 partner wv4: out-GEMM mt0
//  wv1: cohesive scan         | SIMD1 partner wv5: out-GEMM mt1
//  wv2: h-GEMM n=0..4         | SIMD2 partner wv6: h-GEMM n=10..14
//  wv3: h-GEMM n=5..9         | SIMD3 partner wv7: h-GEMM n=15..19
// Scan waves are phase-separated so the lgkm queue never mixes op types:
//   readA burst -> readB burst (issued early, latency hidden under computeA)
//   -> computeA (no LDS) -> computeB (no LDS) -> y write burst.
// In-order lgkm completion + single-type queue => precise lgkmcnt waits.

__global__ __launch_bounds__(512, 2)
void fused_mat_kernel(const float* __restrict__ x,
                      const float* __restrict__ w1,
                      const float* __restrict__ w2,
                      float* __restrict__ out)
{
    // s_h row: [0..255] bulk in padded-4 order (l' = 4c+cm, cm==3 zero pad),
    // [256..319] cohesive jumps. Written by h-GEMM waves as b128 quads.
    __shared__ __attribute__((aligned(16))) float          s_h[2][TC][SROW];
    __shared__ __attribute__((aligned(16))) unsigned short s_y[2][TC][YSS];

    const int tid  = threadIdx.x;
    const int b    = blockIdx.x;
    const int lane = tid & 63;
    const int wv   = tid >> 6;    // 0..7
    const int m    = lane & 15;
    const int q    = lane >> 4;

    const size_t xrow = (size_t)b * TT;

    const bool isG   = (wv == 2) | (wv == 3) | (wv == 6) | (wv == 7);
    const int  hw    = (wv == 2) ? 0 : (wv == 3) ? 1 : (wv == 6) ? 2 : 3;
    const int  nbase = hw * 5;                               // 0 / 5 / 10 / 15

    short8 wfrag[5];  // h-GEMM waves: my 5 W1 A-fragments
    short8 vf[10];    // out-GEMM waves (permuted-k layout)
    uint4  rxc[2][2], rxp[2][2];  // h-GEMM: raw x bits, cur/prev row, per M-tile

    // h-chunk emit: swapped-operand MFMA -> C[col=t][row=l'] -> b128 row writes.
    // Bulk columns (n<16) consume delta-x, cohesive (n>=16) abs-x.
    auto emit = [&](const short8* axv, const short8* adxv, float* dst) {
        #pragma unroll
        for (int mt = 0; mt < 2; ++mt) {
            float* drow = dst + (mt * 16 + m) * SROW + q * 4 + nbase * 16;
            #pragma unroll
            for (int j = 0; j < 5; ++j) {
                const int n = nbase + j;
                floatx4 acc = {0.f, 0.f, 0.f, 0.f};
                acc = __builtin_amdgcn_mfma_f32_16x16x32_bf16(
                        wfrag[j], (n < 16) ? adxv[mt] : axv[mt], acc, 0, 0, 0);
                *(floatx4*)(drow + j * 16) = acc;  // ds_write_b128, imm offset
            }
        }
    };

    if (isG) {
        // ---- my W1 A-fragment slice (folded for n<16, plain for n>=16) ----
        #pragma unroll
        for (int j = 0; j < 5; ++j) {
            const int n = nbase + j;
            #pragma unroll
            for (int jj = 0; jj < 8; ++jj) {
                float v = 0.f;
                if (q < 2) {
                    const int f = q * 8 + jj;
                    if (n < 16) {
                        const int lp = n * 16 + m, c = lp >> 2, cm = lp & 3;
                        if (cm < 3) {
                            const float wa  = w1[(3 * c + 0) * FIN + f];
                            const float wb  = w1[(3 * c + 1) * FIN + f];
                            const float wcc = w1[(3 * c + 2) * FIN + f];
                            v = (cm == 0) ? fmaf(MC01, wb, MC00 * wa)
                              : (cm == 1) ? fmaf(MC00, wb, MC01 * wa)
                                          : MC22 * wcc;
                        }
                    } else {
                        v = w1[(192 + (n - 16) * 16 + m) * FIN + f];
                    }
                }
                wfrag[j][jj] = (short)f2bf_rne(v);
            }
        }
        // ---- prologue: chunk 0 fragments (guarded scalar loads, rowB==0 edge) ----
        short8 ax0[2], adx0[2];
        #pragma unroll
        for (int mt = 0; mt < 2; ++mt) {
            #pragma unroll
            for (int j = 0; j < 8; ++j) {
                float xc = 0.f, xp = 0.f;
                if (q < 2) {
                    const int rowB = mt * 16 + m;
                    xc = x[(xrow + rowB) * FIN + q * 8 + j];
                    if (rowB > 0) xp = x[(xrow + rowB - 1) * FIN + q * 8 + j];
                }
                ax0[mt][j]  = (short)f2bf_rne(xc);
                adx0[mt][j] = (short)f2bf_rne(xc - xp);
            }
        }
        // prefetch raw x rows for chunk 1 (overlaps chunk-0 MFMA+stores)
        if (q < 2) {
            #pragma unroll
            for (int mt = 0; mt < 2; ++mt) {
                const int rowB = TC + mt * 16 + m;
                const float* xc = x + (xrow + rowB) * FIN + q * 8;
                const float* xp = x + (xrow + rowB - 1) * FIN + q * 8;
                rxc[mt][0] = *(const uint4*)xc;  rxc[mt][1] = *(const uint4*)(xc + 4);
                rxp[mt][0] = *(const uint4*)xp;  rxp[mt][1] = *(const uint4*)(xp + 4);
            }
        }
        emit(ax0, adx0, &s_h[0][0][0]);
    } else if (wv == 4 || wv == 5) {
        #pragma unroll
        for (int ks = 0; ks < 10; ++ks) {
            #pragma unroll
            for (int j = 0; j < 8; ++j) {
                const int p = ks * 32 + q * 8 + j;
                unsigned short v = 0;
                if (p < 256) {
                    const int comp = p & 3;
                    if (comp < 3) {
                        const int l = 3 * (p >> 2) + comp;
                        float xv = w2[m * 256 + l];
                        float sp = fmaxf(xv, 0.0f) + log1pf(expf(-fabsf(xv)));
                        v = f2bf_rne(sp);
                    }
                } else {
                    const int l = p - 64;  // 192 + (p-256)
                    float xv = w2[m * 256 + l];
                    float sp = fmaxf(xv, 0.0f) + log1pf(expf(-fabsf(xv)));
                    v = f2bf_rne(sp);
                }
                vf[ks][j] = (short)v;
            }
        }
    }

    // material state. Bulk keeps (trial t, scale rr): sg == rr*t, next trial
    // t' = fma(rr, t, d') — fuses the sg materialization out of the chain.
    float tt0 = 0.f, tt1 = 0.f, tt2 = 0.f, rr = 1.0f, syv = MSY0, pre = AK * MSY0;
    float hist = 0.f;  // coh wave

    __syncthreads();   // chunk 0 visible (full barrier once)

    for (int i = 0; i <= NCHUNK; ++i) {
        if (wv == 0) {
            if (i < NCHUNK) {
                const float* hb = &s_h[i & 1][0][0] + 4 * lane;       // one b128 per step
                unsigned short* yb = &s_y[i & 1][0][0] + 4 * lane;
                floatx4 dvvA[HB], dvvB[HB];
                uint2   yreg[TC];
                // phase 1: read burst A (reads-only queue)
                #pragma unroll
                for (int t = 0; t < HB; ++t) dvvA[t] = *(const floatx4*)(hb + t * SROW);
                SBAR();
                // phase 2: read burst B issued early — latency hides under computeA
                #pragma unroll
                for (int t = 0; t < HB; ++t) dvvB[t] = *(const floatx4*)(hb + (HB + t) * SROW);
                SBAR();
                // phase 3+4: pure-register compute, y collected in registers
                #pragma unroll
                for (int t = 0; t < TC; ++t) {
                    const floatx4 dv = (t < HB) ? dvvA[t] : dvvB[t - HB];
                    tt0 = fmaf(rr, tt0, dv.x);
                    tt1 = fmaf(rr, tt1, dv.y);
                    tt2 = fmaf(rr, tt2, dv.z);
                    const float s01 = tt0 - tt1;
                    const float u   = tt2 * tt2;
                    const float w3  = fmaf(u, 3.0f, 1e-12f);          // clamp absorbed (PSD form)
                    const float bb  = fmaf(tt1, tt1, w3);
                    const float qq  = fmaf(tt0, s01, bb);
                    const float rs  = __builtin_amdgcn_rsqf(qq);
                    const float seq = qq * rs;
                    rr  = fminf(fmaf(pre, rs, BK), 1.0f);
                    syv = fmaxf(syv, fmaf(BK, seq, pre));             // = max(syv, AK*syv+BK*seq)
                    pre = AK * syv;
                    const float sg0 = rr * tt0, sg1 = rr * tt1, sg2 = rr * tt2;
                    unsigned int r0, r1;
                    asm("v_cvt_pk_bf16_f32 %0, %1, %2" : "=v"(r0) : "v"(sg0), "v"(sg1));
                    asm("v_cvt_pk_bf16_f32 %0, %1, %2" : "=v"(r1) : "v"(sg2), "v"(sg2));
                    yreg[t].x = r0; yreg[t].y = r1;
                }
                SBAR();
                // phase 5: y write burst (writes-only queue; drained at BARRIER)
                #pragma unroll
                for (int t = 0; t < TC; ++t)
                    *(uint2*)(yb + t * YSS) = yreg[t];                // pad slot hits vf==0
            }
        } else if (wv == 1) {
            if (i < NCHUNK && lane < 32) {
                const float* hc = &s_h[i & 1][0][0] + 256 + 2 * lane;
                unsigned short* yc = &s_y[i & 1][0][0] + 256 + 2 * lane;
                float2 jvv[TC];
                unsigned int yr[TC];
                #pragma unroll
                for (int t = 0; t < TC; ++t) jvv[t] = *(const float2*)(hc + t * SROW);
                SBAR();
                #pragma unroll
                for (int t = 0; t < TC; ++t) {
                    const float dn = jvv[t].x, ds = jvv[t].y;
                    const float dnp = fmaxf(dn, 0.0f);
                    const float lam = __builtin_amdgcn_sqrtf(fmaxf(fmaf(dnp, dnp, ds * ds), 1e-12f));
                    hist = fmaxf(hist, lam);
                    float dmg = (hist - 0.1f) * __builtin_amdgcn_rcpf(hist * 0.9f);
                    dmg = fminf(fmaxf(dmg, 0.0f), 1.0f);
                    const float om = 1.0f - dmg;
                    const float tn = 50.0f * dn * (dn > 0.0f ? om : 1.0f);
                    const float ts = om * 50.0f * ds;
                    unsigned int r;
                    asm("v_cvt_pk_bf16_f32 %0, %1, %2" : "=v"(r) : "v"(tn), "v"(ts));
                    yr[t] = r;
                }
                SBAR();
                #pragma unroll
                for (int t = 0; t < TC; ++t)
                    *(unsigned int*)(yc + t * YSS) = yr[t];
            }
        } else if (isG) {
            if (i + 1 < NCHUNK) {
                // prefetched raw x -> abs & delta fragments via packed bf16 convert
                short8 ax[2], adx[2];
                #pragma unroll
                for (int mt = 0; mt < 2; ++mt) {
                    const unsigned int wc[8] = {rxc[mt][0].x, rxc[mt][0].y, rxc[mt][0].z, rxc[mt][0].w,
                                                rxc[mt][1].x, rxc[mt][1].y, rxc[mt][1].z, rxc[mt][1].w};
                    const unsigned int wp[8] = {rxp[mt][0].x, rxp[mt][0].y, rxp[mt][0].z, rxp[mt][0].w,
                                                rxp[mt][1].x, rxp[mt][1].y, rxp[mt][1].z, rxp[mt][1].w};
                    union { unsigned int u[4]; short8 s; } Ua, Ud;
                    #pragma unroll
                    for (int p = 0; p < 4; ++p) {
                        const float c0 = u2f(wc[2 * p]),          c1 = u2f(wc[2 * p + 1]);
                        const float d0 = c0 - u2f(wp[2 * p]),     d1 = c1 - u2f(wp[2 * p + 1]);
                        unsigned int va, vd;
                        asm("v_cvt_pk_bf16_f32 %0, %1, %2" : "=v"(va) : "v"(c0), "v"(c1));
                        asm("v_cvt_pk_bf16_f32 %0, %1, %2" : "=v"(vd) : "v"(d0), "v"(d1));
                        Ua.u[p] = (q < 2) ? va : 0u;   // k>=16 zero-pad lanes
                        Ud.u[p] = (q < 2) ? vd : 0u;
                    }
                    ax[mt]  = Ua.s;
                    adx[mt] = Ud.s;
                }
                // issue raw loads for chunk i+2 (stay in flight across the raw barrier)
                if (i + 2 < NCHUNK && q < 2) {
                    #pragma unroll
                    for (int mt = 0; mt < 2; ++mt) {
                        const int rowB = (i + 2) * TC + mt * 16 + m;
                        const float* xc = x + (xrow + rowB) * FIN + q * 8;
                        const float* xp = x + (xrow + rowB - 1) * FIN + q * 8;
                        rxc[mt][0] = *(const uint4*)xc;  rxc[mt][1] = *(const uint4*)(xc + 4);
                        rxp[mt][0] = *(const uint4*)xp;  rxp[mt][1] = *(const uint4*)(xp + 4);
                    }
                }
                emit(ax, adx, &s_h[(i + 1) & 1][0][0]);
            }
        } else {  // wv 4/5: out-GEMM, one M-tile each
            if (i >= 1) {
                const int mt = wv - 4;
                const int tb = (i - 1) * TC;
                const unsigned short* yb = &s_y[(i - 1) & 1][0][0];
                floatx4 a0 = {0.f, 0.f, 0.f, 0.f};
                floatx4 a1 = {0.f, 0.f, 0.f, 0.f};
                #pragma unroll
                for (int ks = 0; ks < 5; ++ks) {
                    const short8* yp = (const short8*)(yb + (mt * 16 + m) * YSS + ks * 32 + q * 8);
                    a0 = __builtin_amdgcn_mfma_f32_16x16x32_bf16(*yp, vf[ks], a0, 0, 0, 0);
                }
                #pragma unroll
                for (int ks = 5; ks < 10; ++ks) {
                    const short8* yp = (const short8*)(yb + (mt * 16 + m) * YSS + ks * 32 + q * 8);
                    a1 = __builtin_amdgcn_mfma_f32_16x16x32_bf16(*yp, vf[ks], a1, 0, 0, 0);
                }
                #pragma unroll
                for (int r = 0; r < 4; ++r)
                    out[(xrow + tb + mt * 16 + q * 4 + r) * FIN + m] = a0[r] + a1[r];
            }
        }
        BARRIER();   // lgkmcnt(0) only — global ops stay in flight
    }
}

extern "C" void kernel_launch(void* const* d_in, const int* in_sizes, int n_in,
                              void* d_out, int out_size, void* d_ws, size_t ws_size,
                              hipStream_t stream) {
    const float* x  = (const float*)d_in[0];   // [256,1024,16] f32
    const float* w1 = (const float*)d_in[1];   // [256,16] f32
    const float* w2 = (const float*)d_in[2];   // [16,256] f32
    float* out = (float*)d_out;                // [256,1024,16] f32
    fused_mat_kernel<<<BATCH, 512, 0, stream>>>(x, w1, w2, out);
}